// Round 1
// baseline (535.073 us; speedup 1.0000x reference)
//
#include <hip/hip_runtime.h>
#include <hip/hip_bf16.h>

#define NN 100000
#define NP 100096            // 782 * 128, padded row count for GEMM
#define EM 1600000
#define EA 200000
#define ET (EM + EA)
#define SB 98                // scan blocks of 1024: 98*1024 >= NN

// k_count fused grid: 4 edges/thread + 8 convert uint2/thread
#define CB 1759
#define TT (CB * 256)        // 450304 threads

// ws layout (4B units):
//  norm[NN] (deg in-place) | cnt[NN] int | cursor[NN] int | bsum[128] int |
//  Wb[16384] (bf16 [j=0..127][k=0..255] packed pairs) |
//  recSC[ET] uint | recEF[ET] uint2 | featsb[64*NP] | rstb[64*NP] | rank16[ET] ushort
#define OFF_NORM 0
#define OFF_CNT  (NN)
#define OFF_CUR  (2*NN)
#define OFF_BSUM (3*NN)
#define OFF_WB   (3*NN + 128)
#define OFF_RSC  (3*NN + 128 + 16384)
#define OFF_REF  (OFF_RSC + ET)
#define OFF_FB   (OFF_REF + 2*ET)
#define OFF_RB   (OFF_FB + 64*NP)
#define OFF_RANK (OFF_RB + 64*NP)

#define UNP_LO(u) __uint_as_float((u) << 16)
#define UNP_HI(u) __uint_as_float((u) & 0xFFFF0000u)

typedef __attribute__((ext_vector_type(8))) short bf16x8;
typedef __attribute__((ext_vector_type(4))) float f32x4;

static __device__ __forceinline__ unsigned pack_bf16x2(float a, float b) {
  union { __hip_bfloat162 v; unsigned u; } cv;
  cv.v = __float22bfloat162_rn(make_float2(a, b));
  return cv.u;
}

// Fused: (1) feats->bf16 conversion (streaming, piggybacks on idle BW/VALU),
// (2) degree + dst-bucket histogram with per-edge arrival rank.
// 4 edges per thread -> 8 atomics in flight per wave before the rank-return
// waits (4x MLP vs 1-edge/thread).
__global__ __launch_bounds__(256) void k_count(
    const int* __restrict__ srcE, const int* __restrict__ dstE,
    const int* __restrict__ dstA, const float* __restrict__ feats,
    float* __restrict__ deg, int* __restrict__ cnt,
    unsigned short* __restrict__ rank16, uint2* __restrict__ fb2) {
  int u = blockIdx.x * 256 + threadIdx.x;

  // feats -> packed bf16 pairs; zero the pad rows. 8 * TT >= NP*32.
#pragma unroll
  for (int k = 0; k < 8; ++k) {
    int p = u + k * TT;
    if (p < NN * 32) {
      float4 f = ((const float4*)feats)[p];
      fb2[p] = make_uint2(pack_bf16x2(f.x, f.y), pack_bf16x2(f.z, f.w));
    } else if (p < NP * 32) {
      fb2[p] = make_uint2(0u, 0u);
    }
  }

  // histogram + rank; 4 * TT >= ET
#pragma unroll
  for (int k = 0; k < 4; ++k) {
    int e = u + k * TT;
    if (e < EM) {
      unsafeAtomicAdd(&deg[srcE[e]], 1.0f);
      rank16[e] = (unsigned short)atomicAdd(&cnt[dstE[e]], 1);
    } else if (e < ET) {
      rank16[e] = (unsigned short)atomicAdd(&cnt[dstA[e - EM]], 1);
    }
  }
}

// norm = rsqrt(deg) in place; build Wb bf16: Wb[j][k] = Wmsg[j][k] (k<128),
// Wskip[j][k-128] (k>=128); row pitch 128 uints (256 bf16)
__global__ __launch_bounds__(256) void k_norm_wt(
    float* __restrict__ norm,
    const float* __restrict__ Wmsg, const float* __restrict__ Wskip,
    unsigned* __restrict__ Wb) {
  int i = blockIdx.x * 256 + threadIdx.x;
  if (i < NN) {
    float dg = norm[i];
    norm[i] = dg > 0.0f ? rsqrtf(dg) : 0.0f;
  }
  if (i < 16384) {
    int j = i >> 7, kk = i & 127;   // kk = uint index within row (2 bf16)
    float a, b;
    if (kk < 64) {
      a = Wmsg[j * 128 + 2 * kk];
      b = Wmsg[j * 128 + 2 * kk + 1];
    } else {
      a = Wskip[j * 128 + 2 * kk - 128];
      b = Wskip[j * 128 + 2 * kk - 127];
    }
    Wb[j * 128 + kk] = pack_bf16x2(a, b);
  }
}

__global__ __launch_bounds__(1024) void k_scan1(const int* __restrict__ cnt,
                                                int* __restrict__ bsum) {
  __shared__ int ws16[16];
  int tid = threadIdx.x, lane = tid & 63, wid = tid >> 6;
  int i = blockIdx.x * 1024 + tid;
  int v = (i < NN) ? cnt[i] : 0;
#pragma unroll
  for (int s = 1; s < 64; s <<= 1) v += __shfl_xor(v, s, 64);
  if (lane == 0) ws16[wid] = v;
  __syncthreads();
  if (tid == 0) {
    int a = 0;
#pragma unroll
    for (int w = 0; w < 16; ++w) a += ws16[w];
    bsum[blockIdx.x] = a;
  }
}

__global__ __launch_bounds__(64) void k_scan2(int* __restrict__ bsum) {
  int lane = threadIdx.x;
  int v0 = (lane < SB) ? bsum[lane] : 0;
  int v1 = (64 + lane < SB) ? bsum[64 + lane] : 0;
  int x0 = v0, x1 = v1;
#pragma unroll
  for (int s = 1; s < 64; s <<= 1) {
    int y = __shfl_up(x0, s, 64); if (lane >= s) x0 += y;
  }
#pragma unroll
  for (int s = 1; s < 64; s <<= 1) {
    int y = __shfl_up(x1, s, 64); if (lane >= s) x1 += y;
  }
  int t0 = __shfl(x0, 63, 64);
  if (lane < SB) bsum[lane] = x0 - v0;
  if (64 + lane < SB) bsum[64 + lane] = t0 + x1 - v1;
}

__global__ __launch_bounds__(1024) void k_scan3(const int* __restrict__ cnt,
                                                const int* __restrict__ bsum,
                                                int* __restrict__ cursor) {
  __shared__ int ws16[16];
  int tid = threadIdx.x, lane = tid & 63, wid = tid >> 6;
  int i = blockIdx.x * 1024 + tid;
  int v = (i < NN) ? cnt[i] : 0;
  int x = v;
#pragma unroll
  for (int s = 1; s < 64; s <<= 1) {
    int y = __shfl_up(x, s, 64); if (lane >= s) x += y;
  }
  if (lane == 63) ws16[wid] = x;
  __syncthreads();
  if (tid == 0) {
    int a = bsum[blockIdx.x];
#pragma unroll
    for (int w = 0; w < 16; ++w) { int t = ws16[w]; ws16[w] = a; a += t; }
  }
  __syncthreads();
  if (i < NN) cursor[i] = ws16[wid] + x - v;   // exclusive start of bucket
}

// bucket by dst, atomic-free: slot = cursor[d] + rank16[e]
__global__ __launch_bounds__(256) void k_fill(
    const int* __restrict__ srcE, const int* __restrict__ dstE,
    const int* __restrict__ srcA, const int* __restrict__ dstA,
    const float* __restrict__ ef, const float* __restrict__ Watt,
    const float* __restrict__ batt, const float* __restrict__ norm,
    const int* __restrict__ cursor, const unsigned short* __restrict__ rank16,
    unsigned* __restrict__ recSC, uint2* __restrict__ recEF) {
  int e = blockIdx.x * 256 + threadIdx.x;
  if (e >= ET) return;
  int s, d;
  float att;
  float4 f;
  if (e < EM) {
    s = srcE[e]; d = dstE[e];
    f = ((const float4*)ef)[e];
    float z = f.x * Watt[0] + f.y * Watt[1] + f.z * Watt[2] + f.w * Watt[3] + batt[0];
    att = 1.0f / (1.0f + __expf(-z));
  } else {
    int ea = e - EM;
    s = srcA[ea]; d = dstA[ea];
    f = make_float4(0.f, 0.f, 0.f, 0.f);
    att = 1.0f / (1.0f + __expf(-batt[0]));
  }
  float c = att * norm[s];
  unsigned q = (unsigned)(c * 32767.0f + 0.5f);
  if (q > 32767u) q = 32767u;
  int slot = cursor[d] + (int)rank16[e];
  recSC[slot] = ((unsigned)s << 15) | q;
  recEF[slot] = make_uint2(pack_bf16x2(f.x, f.y), pack_bf16x2(f.z, f.w));
}

// Pull only: 1 wave per node, no LDS, no barriers -> 32 waves/CU for latency
// hiding. Writes rst row as packed bf16 (rstb).
__global__ __launch_bounds__(256) void k_pull(
    const float* __restrict__ feats, const unsigned* __restrict__ featsb,
    const int* __restrict__ cnt, const int* __restrict__ cursor,
    const float* __restrict__ norm, const unsigned* __restrict__ recSC,
    const uint2* __restrict__ recEF,
    const float* __restrict__ Wedge, const float* __restrict__ bedge,
    unsigned* __restrict__ rstb) {
  int lane = threadIdx.x & 63, wid = threadIdx.x >> 6;
  int n = blockIdx.x * 4 + wid;
  if (n >= NP) return;
  if (n >= NN) { rstb[n * 64 + lane] = 0u; return; }

  int beg = __builtin_amdgcn_readfirstlane(cursor[n]);
  int len = __builtin_amdgcn_readfirstlane(cnt[n]);
  int end = beg + len;
  float2 acc = make_float2(0.f, 0.f);
  int e = beg;
  for (; e + 8 <= end; e += 8) {
    unsigned r0 = recSC[e+0], r1 = recSC[e+1], r2 = recSC[e+2], r3 = recSC[e+3];
    unsigned r4 = recSC[e+4], r5 = recSC[e+5], r6 = recSC[e+6], r7 = recSC[e+7];
    unsigned u0 = featsb[(r0 >> 15) * 64 + lane];
    unsigned u1 = featsb[(r1 >> 15) * 64 + lane];
    unsigned u2 = featsb[(r2 >> 15) * 64 + lane];
    unsigned u3 = featsb[(r3 >> 15) * 64 + lane];
    unsigned u4 = featsb[(r4 >> 15) * 64 + lane];
    unsigned u5 = featsb[(r5 >> 15) * 64 + lane];
    unsigned u6 = featsb[(r6 >> 15) * 64 + lane];
    unsigned u7 = featsb[(r7 >> 15) * 64 + lane];
    float c0 = (float)(r0 & 32767u) * (1.0f / 32767.0f);
    float c1 = (float)(r1 & 32767u) * (1.0f / 32767.0f);
    float c2 = (float)(r2 & 32767u) * (1.0f / 32767.0f);
    float c3 = (float)(r3 & 32767u) * (1.0f / 32767.0f);
    float c4 = (float)(r4 & 32767u) * (1.0f / 32767.0f);
    float c5 = (float)(r5 & 32767u) * (1.0f / 32767.0f);
    float c6 = (float)(r6 & 32767u) * (1.0f / 32767.0f);
    float c7 = (float)(r7 & 32767u) * (1.0f / 32767.0f);
    acc.x += c0 * UNP_LO(u0) + c1 * UNP_LO(u1) + c2 * UNP_LO(u2) + c3 * UNP_LO(u3)
           + c4 * UNP_LO(u4) + c5 * UNP_LO(u5) + c6 * UNP_LO(u6) + c7 * UNP_LO(u7);
    acc.y += c0 * UNP_HI(u0) + c1 * UNP_HI(u1) + c2 * UNP_HI(u2) + c3 * UNP_HI(u3)
           + c4 * UNP_HI(u4) + c5 * UNP_HI(u5) + c6 * UNP_HI(u6) + c7 * UNP_HI(u7);
  }
  for (; e < end; ++e) {
    unsigned r = recSC[e];
    unsigned u = featsb[(r >> 15) * 64 + lane];
    float c = (float)(r & 32767u) * (1.0f / 32767.0f);
    acc.x += c * UNP_LO(u);
    acc.y += c * UNP_HI(u);
  }
  // lane-parallel ef sum over the bucket, butterfly all-reduce
  float4 efa = make_float4(0.f, 0.f, 0.f, 0.f);
  for (int b = beg + lane; b < end; b += 64) {
    uint2 g = recEF[b];
    efa.x += UNP_LO(g.x); efa.y += UNP_HI(g.x);
    efa.z += UNP_LO(g.y); efa.w += UNP_HI(g.y);
  }
#pragma unroll
  for (int s = 1; s < 64; s <<= 1) {
    efa.x += __shfl_xor(efa.x, s, 64);
    efa.y += __shfl_xor(efa.y, s, 64);
    efa.z += __shfl_xor(efa.z, s, 64);
    efa.w += __shfl_xor(efa.w, s, 64);
  }
  float flen = (float)len;
  float nm = norm[n];
  float2 f = ((const float2*)feats)[n * 64 + lane];
  float4 wa = ((const float4*)Wedge)[2 * lane + 0];
  float4 wb = ((const float4*)Wedge)[2 * lane + 1];
  float2 be = ((const float2*)bedge)[lane];
  float tx = wa.x * efa.x + wa.y * efa.y + wa.z * efa.z + wa.w * efa.w;
  float ty = wb.x * efa.x + wb.y * efa.y + wb.z * efa.z + wb.w * efa.w;
  float rx = (acc.x + tx + flen * (be.x + nm * f.x)) * nm;
  float ry = (acc.y + ty + flen * (be.y + nm * f.y)) * nm;
  rstb[n * 64 + lane] = pack_bf16x2(rx, ry);
}

// MFMA GEMM: out[NN][128] = [rstb | featsb](bf16) @ Wb^T-ish + bias.
// Block 256 thr = 4 waves; block covers 128 rows; wave covers 32 rows x 128 cols.
// 16x16x32 bf16 MFMA. A: m=lane&15, k=quad*8+j. B: n=lane&15, k=quad*8+j.
// D: col=lane&15, row=quad*4+reg.
__global__ __launch_bounds__(256) void k_gemm(
    const unsigned* __restrict__ rstb, const unsigned* __restrict__ featsb,
    const unsigned* __restrict__ Wb,
    const float* __restrict__ bmsg, const float* __restrict__ bskip,
    float* __restrict__ out) {
  int lane = threadIdx.x & 63, wid = threadIdx.x >> 6;
  int quad = lane >> 4, l15 = lane & 15;
  int rowt = blockIdx.x * 128 + wid * 32;
  int m0 = rowt + l15;
  int m1 = m0 + 16;

  f32x4 acc0[8], acc1[8];
#pragma unroll
  for (int ct = 0; ct < 8; ++ct) {
    acc0[ct] = (f32x4){0.f, 0.f, 0.f, 0.f};
    acc1[ct] = (f32x4){0.f, 0.f, 0.f, 0.f};
  }

#pragma unroll
  for (int ks = 0; ks < 8; ++ks) {
    int kb = ks * 32;
    const unsigned* Xsrc = (kb < 128) ? rstb : featsb;
    int off = ((kb & 127) >> 1) + quad * 4;    // dword offset in 64-dword row
    bf16x8 a0 = *(const bf16x8*)(Xsrc + m0 * 64 + off);
    bf16x8 a1 = *(const bf16x8*)(Xsrc + m1 * 64 + off);
#pragma unroll
    for (int ct = 0; ct < 8; ++ct) {
      int j = ct * 16 + l15;
      bf16x8 b = *(const bf16x8*)(Wb + j * 128 + (kb >> 1) + quad * 4);
      acc0[ct] = __builtin_amdgcn_mfma_f32_16x16x32_bf16(a0, b, acc0[ct], 0, 0, 0);
      acc1[ct] = __builtin_amdgcn_mfma_f32_16x16x32_bf16(a1, b, acc1[ct], 0, 0, 0);
    }
  }

#pragma unroll
  for (int ct = 0; ct < 8; ++ct) {
    int col = ct * 16 + l15;
    float bia = bmsg[col] + bskip[col];
#pragma unroll
    for (int r = 0; r < 4; ++r) {
      int row0 = rowt + quad * 4 + r;
      if (row0 < NN) out[row0 * 128 + col] = acc0[ct][r] + bia;
      int row1 = row0 + 16;
      if (row1 < NN) out[row1 * 128 + col] = acc1[ct][r] + bia;
    }
  }
}

extern "C" void kernel_launch(void* const* d_in, const int* in_sizes, int n_in,
                              void* d_out, int out_size, void* d_ws, size_t ws_size,
                              hipStream_t stream) {
  const float* feats  = (const float*)d_in[0];
  const float* ef     = (const float*)d_in[1];
  const int*   srcE   = (const int*)d_in[2];
  const int*   dstE   = (const int*)d_in[3];
  const int*   srcA   = (const int*)d_in[4];
  const int*   dstA   = (const int*)d_in[5];
  const float* Wskip  = (const float*)d_in[6];
  const float* bskip  = (const float*)d_in[7];
  const float* Wmsg   = (const float*)d_in[8];
  const float* bmsg   = (const float*)d_in[9];
  const float* Wedge  = (const float*)d_in[10];
  const float* bedge  = (const float*)d_in[11];
  const float* Watt   = (const float*)d_in[12];
  const float* batt   = (const float*)d_in[13];
  float* out = (float*)d_out;
  float* ws  = (float*)d_ws;

  float*          norm   = ws + OFF_NORM;
  int*            cnt    = (int*)(ws + OFF_CNT);
  int*            cursor = (int*)(ws + OFF_CUR);
  int*            bsum   = (int*)(ws + OFF_BSUM);
  unsigned*       Wb     = (unsigned*)(ws + OFF_WB);
  unsigned*       recSC  = (unsigned*)(ws + OFF_RSC);
  uint2*          recEF  = (uint2*)(ws + OFF_REF);
  unsigned*       featsb = (unsigned*)(ws + OFF_FB);
  unsigned*       rstb   = (unsigned*)(ws + OFF_RB);
  unsigned short* rank16 = (unsigned short*)(ws + OFF_RANK);

  hipMemsetAsync(ws, 0, (size_t)(2 * NN) * sizeof(float), stream);  // deg + cnt

  k_count<<<CB, 256, 0, stream>>>(srcE, dstE, dstA, feats, norm, cnt, rank16,
                                  (uint2*)featsb);
  k_norm_wt<<<(NN + 255) / 256, 256, 0, stream>>>(norm, Wmsg, Wskip, Wb);
  k_scan1<<<SB, 1024, 0, stream>>>(cnt, bsum);
  k_scan2<<<1, 64, 0, stream>>>(bsum);
  k_scan3<<<SB, 1024, 0, stream>>>(cnt, bsum, cursor);
  k_fill<<<(ET + 255) / 256, 256, 0, stream>>>(srcE, dstE, srcA, dstA, ef, Watt,
                                               batt, norm, cursor, rank16,
                                               recSC, recEF);
  k_pull<<<NP / 4, 256, 0, stream>>>(feats, featsb, cnt, cursor, norm,
                                     recSC, recEF, Wedge, bedge, rstb);
  k_gemm<<<NP / 128, 256, 0, stream>>>(rstb, featsb, Wb, bmsg, bskip, out);
}